// Round 11
// baseline (91.041 us; speedup 1.0000x reference)
//
#include <hip/hip_runtime.h>
#include <hip/hip_bf16.h>
#include <stdint.h>

#define B_ 4
#define K_ 2048
#define D_ 512
#define H_ 8
#define ATTN_ 128
#define M_ (B_ * K_)   // 8192

typedef __attribute__((ext_vector_type(4))) float f32x4;
typedef __attribute__((ext_vector_type(8))) short bf16x8;
typedef __attribute__((ext_vector_type(8))) unsigned short u16x8;
typedef __attribute__((ext_vector_type(2))) unsigned int u32x2;
typedef __attribute__((ext_vector_type(4))) unsigned int u32x4;

__device__ __forceinline__ unsigned short f2bf(float f) {
    union { float f; unsigned int i; } x; x.f = f;
    unsigned int r = x.i + 0x7fffu + ((x.i >> 16) & 1u);   // RNE
    return (unsigned short)(r >> 16);
}
__device__ __forceinline__ float bf2f(unsigned short u) {
    union { unsigned int i; float f; } x; x.i = ((unsigned int)u) << 16; return x.f;
}
__device__ __forceinline__ unsigned cvtpk(float lo, float hi) {
    unsigned r;
    asm("v_cvt_pk_bf16_f32 %0, %1, %2" : "=v"(r) : "v"(lo), "v"(hi));
    return r;
}
__device__ __forceinline__ void gload_lds16(const unsigned short* g, unsigned short* l) {
    __builtin_amdgcn_global_load_lds(
        (const __attribute__((address_space(1))) void*)g,
        (__attribute__((address_space(3))) void*)l, 16, 0, 0);
}
__device__ __forceinline__ unsigned lds_addr(const void* p) {
    return (unsigned)(unsigned long long)
        (const __attribute__((address_space(3))) void*)p;
}

// ---------------------------------------------------------------------------
// fp32 -> bf16 conversion: weights only (4 tensors)
// ---------------------------------------------------------------------------
struct Cvt { const float* s; unsigned short* d; int n8; };
struct CvtA { Cvt c[4]; };

__global__ __launch_bounds__(256)
void cvt_multi(CvtA a) {
    const Cvt c = a.c[blockIdx.y];
    const float4* s4 = (const float4*)c.s;
    u16x8* d8 = (u16x8*)c.d;
    for (int g = blockIdx.x * 256 + threadIdx.x; g < c.n8; g += gridDim.x * 256) {
        float4 f0 = s4[2 * g], f1 = s4[2 * g + 1];
        u16x8 o;
        o[0] = f2bf(f0.x); o[1] = f2bf(f0.y); o[2] = f2bf(f0.z); o[3] = f2bf(f0.w);
        o[4] = f2bf(f1.x); o[5] = f2bf(f1.y); o[6] = f2bf(f1.z); o[7] = f2bf(f1.w);
        d8[g] = o;
    }
}

// ---------------------------------------------------------------------------
// persist-v2 QKV GEMM (barrier-free K-loop):
//   C_z[8192,512] = A_z(fp32) @ W_z^T + b_z, z folded into fused-M grid.
// Fixes of r10's two measured failures:
//  (1) LDS W is CHUNK-MAJOR [kchunk 64][row 64][8]: a wave's b128 read gives
//      every consecutive 8-lane group 8 consecutive 16B row-slots ->
//      conflict-free (same beat structure as r2-validated layout, 0 conflicts
//      measured in r4). No XOR needed. 64 KB -> 2 blocks/CU (16 waves).
//  (2) 3-deep A-prefetch ring (static by full unroll) + 16 waves/CU ->
//      ~100 outstanding loads/CU; latency-bound fixed by MLP, not barriers.
// W staged once (one __syncthreads); K-loop has NO synchronization at all.
// Grid 768: id = nt*96 + mg -> id%8 = mg%8, so all 8 n-tiles of an m-group
// land on one XCD (A-tile L2-reuse x8). fp32->bf16 via v_cvt_pk (RNE).
// ---------------------------------------------------------------------------
struct PArgs {
    const float* A[3];
    const unsigned short* Wt[3];
    const float* bias[3];
    unsigned short* C[3];
};

__global__ __launch_bounds__(512, 4)
void gemm_qkv_persist(PArgs args)
{
    __shared__ unsigned short Wl[64 * 512];      // 64 KB, chunk-major

    const int id = blockIdx.x;                   // 0..767
    const int nt = id / 96;                      // 0..7
    const int mg = id - nt * 96;                 // 0..95 (XCD = mg%8)
    const int z  = mg >> 5;
    const int bm = (mg & 31) * 256;
    const int bn = nt * 64;

    const float* Az = args.A[z];
    const unsigned short* Wz = args.Wt[z] + (size_t)bn * D_;
    const float* biz = args.bias[z];
    unsigned short* Cz = args.C[z];

    const int tid = threadIdx.x;
    const int w   = tid >> 6;                    // wave 0..7
    const int l   = tid & 63;
    const int lr  = l & 15;
    const int lhi = l >> 4;
    const int m0  = bm + w * 32;                 // this wave's 32-row strip

    f32x4 acc[2][4];
    #pragma unroll
    for (int fm = 0; fm < 2; ++fm)
        #pragma unroll
        for (int fn = 0; fn < 4; ++fn) acc[fm][fn] = (f32x4){0.f, 0.f, 0.f, 0.f};

    float4 fa[3][2][2];   // A-prefetch ring [slot][fm][half], static-indexed

    auto loadA = [&](int kk, int s) {
        #pragma unroll
        for (int fm = 0; fm < 2; ++fm) {
            const float* src = Az + (size_t)(m0 + fm * 16 + lr) * D_ + kk * 32 + lhi * 8;
            fa[s][fm][0] = *(const float4*)src;
            fa[s][fm][1] = *(const float4*)(src + 4);
        }
    };

    // A prologue loads first (overlap W staging latency)
    loadA(0, 0); loadA(1, 1); loadA(2, 2);

    // ---- stage W once, chunk-major: dest slot (kc*64 + lane) ----
    #pragma unroll
    for (int it = 0; it < 8; ++it) {
        const int kc = it * 8 + w;               // 0..63, wave-uniform
        gload_lds16(Wz + (size_t)l * D_ + kc * 8, &Wl[kc * 512]);
    }
    __syncthreads();                             // the ONLY barrier

    #pragma unroll
    for (int kk = 0; kk < 16; ++kk) {            // K = 512 = 16 x 32
        const int s = kk % 3;

        // convert A frags (v_cvt_pk_bf16_f32, RNE), memory order k=0..7
        bf16x8 af[2];
        #pragma unroll
        for (int fm = 0; fm < 2; ++fm) {
            const float4 f0 = fa[s][fm][0], f1 = fa[s][fm][1];
            union { u32x4 u; bf16x8 b; } cv;
            cv.u[0] = cvtpk(f0.x, f0.y);
            cv.u[1] = cvtpk(f0.z, f0.w);
            cv.u[2] = cvtpk(f1.x, f1.y);
            cv.u[3] = cvtpk(f1.z, f1.w);
            af[fm] = cv.b;
        }
        if (kk < 13) loadA(kk + 3, s);           // refill ring slot

        // B frags from chunk-major W (conflict-free)
        bf16x8 bfr[4];
        #pragma unroll
        for (int fn = 0; fn < 4; ++fn)
            bfr[fn] = *(const bf16x8*)&Wl[(kk * 4 + lhi) * 512 + (fn * 16 + lr) * 8];

        #pragma unroll
        for (int fm = 0; fm < 2; ++fm)
            #pragma unroll
            for (int fn = 0; fn < 4; ++fn)
                acc[fm][fn] = __builtin_amdgcn_mfma_f32_16x16x32_bf16(
                    af[fm], bfr[fn], acc[fm][fn], 0, 0, 0);
    }

    // ---- epilogue ----
    float bv[4];
    #pragma unroll
    for (int fn = 0; fn < 4; ++fn) bv[fn] = biz[bn + fn * 16 + lr];

    #pragma unroll
    for (int fm = 0; fm < 2; ++fm)
        #pragma unroll
        for (int fn = 0; fn < 4; ++fn)
            #pragma unroll
            for (int rr = 0; rr < 4; ++rr) {
                const int row = m0 + fm * 16 + lhi * 4 + rr;
                const int col = bn + fn * 16 + lr;
                Cz[(size_t)row * D_ + col] = f2bf(acc[fm][fn][rr] + bv[fn]);
            }
}

// ---------------------------------------------------------------------------
// bf16 MFMA GEMM (round-2 validated) — output projection only.
// ---------------------------------------------------------------------------
template<bool OUT_BF16>
__global__ __launch_bounds__(512)
void gemm_bf16k(const unsigned short* __restrict__ A,
                const unsigned short* __restrict__ W,
                const float* __restrict__ bias,
                void* __restrict__ C)
{
    __shared__ unsigned short As[2][128 * 64];
    __shared__ unsigned short Bs[2][128 * 64];

    const int id  = blockIdx.x;
    const int swz = (id & 7) * 32 + (id >> 3);
    const int bm  = (swz & 63) * 128;
    const int bn  = (swz >> 6) * 128;

    const int tid = threadIdx.x;
    const int w   = tid >> 6;
    const int l   = tid & 63;
    const int lr  = l & 15;
    const int lhi = l >> 4;
    const int wm  = (w >> 1) * 32;
    const int wn  = (w & 1) * 64;

    f32x4 acc[2][4];
    #pragma unroll
    for (int i = 0; i < 2; ++i)
        #pragma unroll
        for (int j = 0; j < 4; ++j) acc[i][j] = (f32x4){0.f, 0.f, 0.f, 0.f};

    auto stage = [&](int buf, int t) {
        const int k0 = t * 64;
        #pragma unroll
        for (int it = 0; it < 2; ++it) {
            const int f  = it * 64 + l;
            const int r  = w * 16 + (f >> 3);
            const int cs = (f & 7) ^ (r & 7);
            gload_lds16(A + (size_t)(bm + r) * D_ + k0 + cs * 8,
                        &As[buf][(w * 128 + it * 64) * 8]);
        }
        #pragma unroll
        for (int it = 0; it < 2; ++it) {
            const int f  = it * 64 + l;
            const int r  = w * 16 + (f >> 3);
            const int cs = (f & 7) ^ (r & 7);
            gload_lds16(W + (size_t)(bn + r) * D_ + k0 + cs * 8,
                        &Bs[buf][(w * 128 + it * 64) * 8]);
        }
    };

    stage(0, 0);
    __syncthreads();

    int buf = 0;
    for (int t = 0; t < 8; ++t) {
        if (t < 7) stage(buf ^ 1, t + 1);
        #pragma unroll
        for (int kk = 0; kk < 2; ++kk) {
            bf16x8 af[2], bfr[4];
            #pragma unroll
            for (int fm = 0; fm < 2; ++fm) {
                const int row = wm + fm * 16 + lr;
                const int ch  = (kk * 4 + lhi) ^ (lr & 7);
                af[fm] = *(const bf16x8*)&As[buf][row * 64 + ch * 8];
            }
            #pragma unroll
            for (int fn = 0; fn < 4; ++fn) {
                const int row = wn + fn * 16 + lr;
                const int ch  = (kk * 4 + lhi) ^ (lr & 7);
                bfr[fn] = *(const bf16x8*)&Bs[buf][row * 64 + ch * 8];
            }
            #pragma unroll
            for (int fm = 0; fm < 2; ++fm)
                #pragma unroll
                for (int fn = 0; fn < 4; ++fn)
                    acc[fm][fn] = __builtin_amdgcn_mfma_f32_16x16x32_bf16(
                        af[fm], bfr[fn], acc[fm][fn], 0, 0, 0);
        }
        __syncthreads();
        buf ^= 1;
    }

    float bv[4];
    #pragma unroll
    for (int fn = 0; fn < 4; ++fn) bv[fn] = bias[bn + wn + fn * 16 + lr];

    #pragma unroll
    for (int fm = 0; fm < 2; ++fm)
        #pragma unroll
        for (int fn = 0; fn < 4; ++fn)
            #pragma unroll
            for (int rr = 0; rr < 4; ++rr) {
                const int row = bm + wm + fm * 16 + lhi * 4 + rr;
                const int col = bn + wn + fn * 16 + lr;
                const float val = acc[fm][fn][rr] + bv[fn];
                if (OUT_BF16)
                    ((unsigned short*)C)[(size_t)row * 512 + col] = f2bf(val);
                else
                    ((float*)C)[(size_t)row * 512 + col] = val;
            }
}

// ---------------------------------------------------------------------------
// MFMA banded-causal local attention (round-3 validated, unchanged).
// ---------------------------------------------------------------------------
__global__ __launch_bounds__(256)
void attn_mfma(const unsigned short* __restrict__ qb,
               const unsigned short* __restrict__ kb,
               const unsigned short* __restrict__ vb,
               unsigned short* __restrict__ ob)
{
    __shared__ unsigned short Ksh[192 * 64];
    __shared__ unsigned short Vsh[4 * 192 * 16];
    __shared__ unsigned short Psh[4 * 16 * 200];

    const int flat = blockIdx.x + 32 * (blockIdx.y + 8 * blockIdx.z);
    const int lg   = (flat & 7) * 128 + (flat >> 3);
    const int tile = lg & 31;
    const int h    = (lg >> 5) & 7;
    const int b    = lg >> 8;

    const int i0 = tile * 64;
    const int j0 = i0 - 128;
    const int tid = threadIdx.x;
    const int w   = tid >> 6;
    const int l   = tid & 63;
    const int lr  = l & 15;
    const int lhi = l >> 4;
    const float scale = 0.0220970869120796f;

    const size_t hbase = ((size_t)b * K_) * 512 + (size_t)h * 64;
    const unsigned short* kh = kb + hbase;
    const unsigned short* vh = vb + hbase;
    const unsigned short* qh = qb + hbase;
    unsigned short* oh = ob + hbase;

    #pragma unroll
    for (int it = 0; it < 6; ++it) {
        const int cg  = it * 4 + w;
        const int cid = cg * 64 + l;
        const int r = cid >> 3, c = cid & 7;
        const int cs = c ^ (r & 7);
        int j = j0 + r; if (j < 0) j = 0;
        gload_lds16(kh + (size_t)j * 512 + cs * 8, &Ksh[cg * 64 * 8]);
    }
    #pragma unroll
    for (int it = 0; it < 6; ++it) {
        const int cg  = it * 4 + w;
        const int cid = cg * 64 + l;
        const int blk = cid / 384;
        const int rem = cid - blk * 384;
        const int prow = rem >> 1, hf = rem & 1;
        const int a = prow >> 2, bb = prow & 3;
        const int k = (a < 24) ? (8 * a + bb) : (8 * (a - 24) + 4 + bb);
        int j = j0 + k; if (j < 0) j = 0;
        gload_lds16(vh + (size_t)j * 512 + blk * 16 + hf * 8, &Vsh[cg * 64 * 8]);
    }

    bf16x8 qa[2];
    {
        const unsigned short* qrow = qh + (size_t)(i0 + 16 * w + lr) * 512;
        qa[0] = *(const bf16x8*)(qrow + lhi * 8);
        qa[1] = *(const bf16x8*)(qrow + 32 + lhi * 8);
    }
    __syncthreads();

    const int jcbase = w & ~1;
    f32x4 sacc[10];
    #pragma unroll
    for (int jc = 0; jc < 10; ++jc) sacc[jc] = (f32x4){0.f, 0.f, 0.f, 0.f};

    __builtin_amdgcn_s_setprio(1);
    #pragma unroll
    for (int kk = 0; kk < 2; ++kk) {
        const int ch = (kk * 4 + lhi) ^ (lr & 7);
        #pragma unroll
        for (int jc = 0; jc < 10; ++jc) {
            const int row = (jcbase + jc) * 16 + lr;
            bf16x8 kf = *(const bf16x8*)&Ksh[row * 64 + ch * 8];
            sacc[jc] = __builtin_amdgcn_mfma_f32_16x16x32_bf16(
                qa[kk], kf, sacc[jc], 0, 0, 0);
        }
    }
    __builtin_amdgcn_s_setprio(0);

    unsigned short* myP = &Psh[w * 3200];
    const int lo0 = 128 - i0;
    float lsum[4] = {0.f, 0.f, 0.f, 0.f};
    #pragma unroll
    for (int jc = 0; jc < 10; ++jc) {
        const int jcol = (jcbase + jc) * 16 + lr;
        #pragma unroll
        for (int rr = 0; rr < 4; ++rr) {
            const int iloc = 16 * w + 4 * lhi + rr;
            const bool ok = (jcol >= iloc) && (jcol <= iloc + ATTN_) && (jcol >= lo0);
            const float p = ok ? __expf(fminf(sacc[jc][rr] * scale, 80.f)) : 0.f;
            lsum[rr] += p;
            myP[(4 * lhi + rr) * 200 + jcol] = f2bf(p);
        }
    }
    #pragma unroll
    for (int rr = 0; rr < 4; ++rr) {
        float s = lsum[rr];
        s += __shfl_xor(s, 1, 16);
        s += __shfl_xor(s, 2, 16);
        s += __shfl_xor(s, 4, 16);
        s += __shfl_xor(s, 8, 16);
        lsum[rr] = s;
    }

    const int kcbase = w >> 1;
    f32x4 oacc[4];
    #pragma unroll
    for (int fn = 0; fn < 4; ++fn) oacc[fn] = (f32x4){0.f, 0.f, 0.f, 0.f};
    const unsigned vbase = lds_addr(&Vsh[0]) + (unsigned)(l * 8);

    for (int kc5 = 0; kc5 < 5; ++kc5) {
        const int kc = kcbase + kc5;
        bf16x8 pa = *(const bf16x8*)&myP[lr * 200 + kc * 32 + lhi * 8];
        u32x2 vlo[4], vhi[4];
        #pragma unroll
        for (int fn = 0; fn < 4; ++fn) {
            const unsigned addr = vbase + (unsigned)((fn * 3072 + kc * 256) * 2);
            asm volatile("ds_read_b64_tr_b16 %0, %1" : "=v"(vlo[fn]) : "v"(addr));
            asm volatile("ds_read_b64_tr_b16 %0, %1 offset:3072"
                         : "=v"(vhi[fn]) : "v"(addr));
        }
        asm volatile("s_waitcnt lgkmcnt(0)" ::: "memory");
        __builtin_amdgcn_sched_barrier(0);
        __builtin_amdgcn_s_setprio(1);
        #pragma unroll
        for (int fn = 0; fn < 4; ++fn) {
            union { u32x2 h[2]; bf16x8 v; } u;
            u.h[0] = vlo[fn]; u.h[1] = vhi[fn];
            oacc[fn] = __builtin_amdgcn_mfma_f32_16x16x32_bf16(
                pa, u.v, oacc[fn], 0, 0, 0);
        }
        __builtin_amdgcn_s_setprio(0);
    }

    float inv[4];
    #pragma unroll
    for (int rr = 0; rr < 4; ++rr) inv[rr] = 1.f / lsum[rr];
    #pragma unroll
    for (int fn = 0; fn < 4; ++fn)
        #pragma unroll
        for (int rr = 0; rr < 4; ++rr) {
            const int row = i0 + 16 * w + 4 * lhi + rr;
            oh[(size_t)row * 512 + fn * 16 + lr] = f2bf(oacc[fn][rr] * inv[rr]);
        }
}

// ---------------------------------------------------------------------------
extern "C" void kernel_launch(void* const* d_in, const int* in_sizes, int n_in,
                              void* d_out, int out_size, void* d_ws, size_t ws_size,
                              hipStream_t stream)
{
    const float* query = (const float*)d_in[0];
    const float* key   = (const float*)d_in[1];
    const float* value = (const float*)d_in[2];
    const float* W_q   = (const float*)d_in[3];
    const float* b_q   = (const float*)d_in[4];
    const float* W_k   = (const float*)d_in[5];
    const float* b_k   = (const float*)d_in[6];
    const float* W_v   = (const float*)d_in[7];
    const float* b_v   = (const float*)d_in[8];
    const float* W_o   = (const float*)d_in[9];
    const float* b_o   = (const float*)d_in[10];
    float* out = (float*)d_out;

    const size_t NX = (size_t)M_ * 512;
    const size_t NW = 512 * 512;
    unsigned short* wqb = (unsigned short*)d_ws;
    unsigned short* wkb = wqb + NW;
    unsigned short* wvb = wkb + NW;
    unsigned short* wob = wvb + NW;
    unsigned short* qp  = wob + NW;
    unsigned short* kp  = qp + NX;
    unsigned short* vp  = kp + NX;
    unsigned short* ap  = vp + NX;

    const int NW8 = (int)(NW / 8);

    CvtA a;
    a.c[0] = { W_q, wqb, NW8 };
    a.c[1] = { W_k, wkb, NW8 };
    a.c[2] = { W_v, wvb, NW8 };
    a.c[3] = { W_o, wob, NW8 };
    cvt_multi<<<dim3(32, 4), 256, 0, stream>>>(a);

    PArgs qa;
    qa.A[0] = query; qa.A[1] = key; qa.A[2] = value;
    qa.Wt[0] = wqb;  qa.Wt[1] = wkb; qa.Wt[2] = wvb;
    qa.bias[0] = b_q; qa.bias[1] = b_k; qa.bias[2] = b_v;
    qa.C[0] = qp; qa.C[1] = kp; qa.C[2] = vp;
    gemm_qkv_persist<<<768, 512, 0, stream>>>(qa);   // id = nt*96 + (z*32+mg)

    attn_mfma<<<dim3(32, 8, 4), 256, 0, stream>>>(qp, kp, vp, ap);

    gemm_bf16k<false><<<256, 512, 0, stream>>>(ap, wob, b_o, out);
}

// Round 12
// 59.888 us; speedup vs baseline: 1.5202x; 1.5202x over previous
//
#include <hip/hip_runtime.h>
#include <hip/hip_bf16.h>
#include <stdint.h>

#define B_ 4
#define K_ 2048
#define D_ 512
#define H_ 8
#define ATTN_ 128
#define M_ (B_ * K_)   // 8192

typedef __attribute__((ext_vector_type(4))) float f32x4;
typedef __attribute__((ext_vector_type(8))) short bf16x8;
typedef __attribute__((ext_vector_type(8))) unsigned short u16x8;
typedef __attribute__((ext_vector_type(2))) unsigned int u32x2;
typedef __attribute__((ext_vector_type(4))) unsigned int u32x4;

__device__ __forceinline__ unsigned short f2bf(float f) {
    union { float f; unsigned int i; } x; x.f = f;
    unsigned int r = x.i + 0x7fffu + ((x.i >> 16) & 1u);   // RNE
    return (unsigned short)(r >> 16);
}
__device__ __forceinline__ float bf2f(unsigned short u) {
    union { unsigned int i; float f; } x; x.i = ((unsigned int)u) << 16; return x.f;
}
__device__ __forceinline__ void gload_lds16(const unsigned short* g, unsigned short* l) {
    __builtin_amdgcn_global_load_lds(
        (const __attribute__((address_space(1))) void*)g,
        (__attribute__((address_space(3))) void*)l, 16, 0, 0);
}
__device__ __forceinline__ unsigned lds_addr(const void* p) {
    return (unsigned)(unsigned long long)
        (const __attribute__((address_space(3))) void*)p;
}

// ---------------------------------------------------------------------------
// fp32 -> bf16 conversion: weights only (4 tensors)
// ---------------------------------------------------------------------------
struct Cvt { const float* s; unsigned short* d; int n8; };
struct CvtA { Cvt c[4]; };

__global__ __launch_bounds__(256)
void cvt_multi(CvtA a) {
    const Cvt c = a.c[blockIdx.y];
    const float4* s4 = (const float4*)c.s;
    u16x8* d8 = (u16x8*)c.d;
    for (int g = blockIdx.x * 256 + threadIdx.x; g < c.n8; g += gridDim.x * 256) {
        float4 f0 = s4[2 * g], f1 = s4[2 * g + 1];
        u16x8 o;
        o[0] = f2bf(f0.x); o[1] = f2bf(f0.y); o[2] = f2bf(f0.z); o[3] = f2bf(f0.w);
        o[4] = f2bf(f1.x); o[5] = f2bf(f1.y); o[6] = f2bf(f1.z); o[7] = f2bf(f1.w);
        d8[g] = o;
    }
}

// ---------------------------------------------------------------------------
// m97-replica GEMM: C[8192,512] = A @ W^T + bias.
// 128x128 tile, BK=64, 256 threads = 4 waves (2x2 grid, 64x64/wave, 4x4
// 16x16x32 frags). SINGLE-buffered 32 KB LDS, 2 barriers/K-step,
// __launch_bounds__(256,3) -> ~3 blocks/CU co-resident: cross-block wave
// overlap hides load latency + barrier drains (m97/m114 mechanism; the
// missing ingredient in r2-r11 which all ran 1 block/CU or starved).
// A_FP32 (QKV): A fp32 reg-staged, loads for t+1 issued BEFORE compute(t)
// (a full compute phase of latency cover), cvt(RNE)+ds_write after the
// read-drain barrier. Else (out-proj): A bf16 via gload_lds like W.
// Swizzle: r2-validated row-stride-64 XOR (0 conflicts measured r4).
// Grid: nt-consecutive XCD map -> 4 n-tile blocks sharing an A-tile run
// concurrently on one XCD (A-tile L2-resident, ~2 MB/XCD working set).
// ---------------------------------------------------------------------------
struct GArgs {
    const void* A[3];
    const unsigned short* Wt[3];
    const float* bias[3];
    void* C[3];
};

template<bool A_FP32>
__global__ __launch_bounds__(256, 3)
void gemm128(GArgs args)
{
    __shared__ unsigned short As[128 * 64];      // 16 KB
    __shared__ unsigned short Bs[128 * 64];      // 16 KB

    const int id = blockIdx.x;
    const int lg = (id & 7) * (gridDim.x >> 3) + (id >> 3);  // XCD-contiguous
    const int g  = lg >> 2;                      // m-group (shares A-tile)
    const int nt = lg & 3;
    const int z  = A_FP32 ? (g >> 6) : 0;
    const int mt = A_FP32 ? (g & 63) : g;
    const int bm = mt * 128;
    const int bn = nt * 128;

    const void* Az = args.A[z];
    const unsigned short* Wz = args.Wt[z];
    const float* biz = args.bias[z];
    void* Cz = args.C[z];

    const int tid = threadIdx.x;
    const int w   = tid >> 6;                    // wave 0..3
    const int l   = tid & 63;
    const int lr  = l & 15;
    const int lhi = l >> 4;
    const int wm  = (w >> 1) * 64;               // 2x2 wave grid
    const int wn  = (w & 1) * 64;

    f32x4 acc[4][4];
    #pragma unroll
    for (int m = 0; m < 4; ++m)
        #pragma unroll
        for (int n = 0; n < 4; ++n) acc[m][n] = (f32x4){0.f, 0.f, 0.f, 0.f};

    float4 fa[4][2];   // in-flight fp32 A tile (32 VGPR)

    auto loadA_f32 = [&](int t) {                // 8 float4 / thread
        #pragma unroll
        for (int q = 0; q < 4; ++q) {
            const int cid = q * 256 + tid;       // 1024 chunks: 128 rows x 8
            const int r = cid >> 3;
            const int c = (cid & 7) ^ (r & 7);   // load-side XOR permutation
            const float* src = (const float*)Az + (size_t)(bm + r) * D_ + t * 64 + c * 8;
            fa[q][0] = *(const float4*)src;
            fa[q][1] = *(const float4*)(src + 4);
        }
    };
    auto writeA_f32 = [&]() {                    // cvt + 4 ds_write_b128
        #pragma unroll
        for (int q = 0; q < 4; ++q) {
            const int cid = q * 256 + tid;
            u16x8 o;
            o[0] = f2bf(fa[q][0].x); o[1] = f2bf(fa[q][0].y);
            o[2] = f2bf(fa[q][0].z); o[3] = f2bf(fa[q][0].w);
            o[4] = f2bf(fa[q][1].x); o[5] = f2bf(fa[q][1].y);
            o[6] = f2bf(fa[q][1].z); o[7] = f2bf(fa[q][1].w);
            *(u16x8*)&As[cid * 8] = o;           // linear dest: conflict-free
        }
    };
    auto stageA_b16 = [&](int t) {               // 4 gload_lds / wave
        #pragma unroll
        for (int it = 0; it < 4; ++it) {
            const int cg  = it * 4 + w;
            const int cid = cg * 64 + l;
            const int r = cid >> 3;
            const int c = (cid & 7) ^ (r & 7);
            gload_lds16((const unsigned short*)Az + (size_t)(bm + r) * D_ + t * 64 + c * 8,
                        &As[cg * 512]);
        }
    };
    auto stageB = [&](int t) {
        #pragma unroll
        for (int it = 0; it < 4; ++it) {
            const int cg  = it * 4 + w;
            const int cid = cg * 64 + l;
            const int r = cid >> 3;
            const int c = (cid & 7) ^ (r & 7);
            gload_lds16(Wz + (size_t)(bn + r) * D_ + t * 64 + c * 8,
                        &Bs[cg * 512]);
        }
    };

    // Prologue: stage tile 0, full drain.
    if (A_FP32) { loadA_f32(0); writeA_f32(); }
    else        { stageA_b16(0); }
    stageB(0);
    __syncthreads();

    for (int t = 0; t < 8; ++t) {                // K = 512 = 8 x 64
        if (A_FP32 && t < 7) loadA_f32(t + 1);   // global->reg: issue early,
                                                 // a full compute phase ahead
        #pragma unroll
        for (int kk = 0; kk < 2; ++kk) {
            bf16x8 af[4], bfr[4];
            #pragma unroll
            for (int fm = 0; fm < 4; ++fm) {
                const int row = wm + fm * 16 + lr;
                const int sl  = (kk * 4 + lhi) ^ (row & 7);
                af[fm] = *(const bf16x8*)&As[row * 64 + sl * 8];
            }
            #pragma unroll
            for (int fn = 0; fn < 4; ++fn) {
                const int row = wn + fn * 16 + lr;
                const int sl  = (kk * 4 + lhi) ^ (row & 7);
                bfr[fn] = *(const bf16x8*)&Bs[row * 64 + sl * 8];
            }
            #pragma unroll
            for (int fm = 0; fm < 4; ++fm)
                #pragma unroll
                for (int fn = 0; fn < 4; ++fn)
                    acc[fm][fn] = __builtin_amdgcn_mfma_f32_16x16x32_bf16(
                        af[fm], bfr[fn], acc[fm][fn], 0, 0, 0);
        }
        __syncthreads();                         // all LDS reads of tile t done
        if (t < 7) {
            if (A_FP32) writeA_f32();            // compiler waits fa deps
            else        stageA_b16(t + 1);
            stageB(t + 1);
            __syncthreads();                     // drains vmcnt+lgkm: tile t+1 ready
        }
    }

    // Epilogue
    float bv[4];
    #pragma unroll
    for (int fn = 0; fn < 4; ++fn) bv[fn] = biz[bn + wn + fn * 16 + lr];

    #pragma unroll
    for (int fm = 0; fm < 4; ++fm)
        #pragma unroll
        for (int fn = 0; fn < 4; ++fn)
            #pragma unroll
            for (int rr = 0; rr < 4; ++rr) {
                const int row = bm + wm + fm * 16 + lhi * 4 + rr;
                const int col = bn + wn + fn * 16 + lr;
                const float val = acc[fm][fn][rr] + bv[fn];
                if (A_FP32)   // QKV -> bf16 out
                    ((unsigned short*)Cz)[(size_t)row * 512 + col] = f2bf(val);
                else          // out-proj -> fp32 out
                    ((float*)Cz)[(size_t)row * 512 + col] = val;
            }
}

// ---------------------------------------------------------------------------
// MFMA banded-causal local attention (round-3 validated, unchanged).
// ---------------------------------------------------------------------------
__global__ __launch_bounds__(256)
void attn_mfma(const unsigned short* __restrict__ qb,
               const unsigned short* __restrict__ kb,
               const unsigned short* __restrict__ vb,
               unsigned short* __restrict__ ob)
{
    __shared__ unsigned short Ksh[192 * 64];
    __shared__ unsigned short Vsh[4 * 192 * 16];
    __shared__ unsigned short Psh[4 * 16 * 200];

    const int flat = blockIdx.x + 32 * (blockIdx.y + 8 * blockIdx.z);
    const int lg   = (flat & 7) * 128 + (flat >> 3);
    const int tile = lg & 31;
    const int h    = (lg >> 5) & 7;
    const int b    = lg >> 8;

    const int i0 = tile * 64;
    const int j0 = i0 - 128;
    const int tid = threadIdx.x;
    const int w   = tid >> 6;
    const int l   = tid & 63;
    const int lr  = l & 15;
    const int lhi = l >> 4;
    const float scale = 0.0220970869120796f;

    const size_t hbase = ((size_t)b * K_) * 512 + (size_t)h * 64;
    const unsigned short* kh = kb + hbase;
    const unsigned short* vh = vb + hbase;
    const unsigned short* qh = qb + hbase;
    unsigned short* oh = ob + hbase;

    #pragma unroll
    for (int it = 0; it < 6; ++it) {
        const int cg  = it * 4 + w;
        const int cid = cg * 64 + l;
        const int r = cid >> 3, c = cid & 7;
        const int cs = c ^ (r & 7);
        int j = j0 + r; if (j < 0) j = 0;
        gload_lds16(kh + (size_t)j * 512 + cs * 8, &Ksh[cg * 64 * 8]);
    }
    #pragma unroll
    for (int it = 0; it < 6; ++it) {
        const int cg  = it * 4 + w;
        const int cid = cg * 64 + l;
        const int blk = cid / 384;
        const int rem = cid - blk * 384;
        const int prow = rem >> 1, hf = rem & 1;
        const int a = prow >> 2, bb = prow & 3;
        const int k = (a < 24) ? (8 * a + bb) : (8 * (a - 24) + 4 + bb);
        int j = j0 + k; if (j < 0) j = 0;
        gload_lds16(vh + (size_t)j * 512 + blk * 16 + hf * 8, &Vsh[cg * 64 * 8]);
    }

    bf16x8 qa[2];
    {
        const unsigned short* qrow = qh + (size_t)(i0 + 16 * w + lr) * 512;
        qa[0] = *(const bf16x8*)(qrow + lhi * 8);
        qa[1] = *(const bf16x8*)(qrow + 32 + lhi * 8);
    }
    __syncthreads();

    const int jcbase = w & ~1;
    f32x4 sacc[10];
    #pragma unroll
    for (int jc = 0; jc < 10; ++jc) sacc[jc] = (f32x4){0.f, 0.f, 0.f, 0.f};

    __builtin_amdgcn_s_setprio(1);
    #pragma unroll
    for (int kk = 0; kk < 2; ++kk) {
        const int ch = (kk * 4 + lhi) ^ (lr & 7);
        #pragma unroll
        for (int jc = 0; jc < 10; ++jc) {
            const int row = (jcbase + jc) * 16 + lr;
            bf16x8 kf = *(const bf16x8*)&Ksh[row * 64 + ch * 8];
            sacc[jc] = __builtin_amdgcn_mfma_f32_16x16x32_bf16(
                qa[kk], kf, sacc[jc], 0, 0, 0);
        }
    }
    __builtin_amdgcn_s_setprio(0);

    unsigned short* myP = &Psh[w * 3200];
    const int lo0 = 128 - i0;
    float lsum[4] = {0.f, 0.f, 0.f, 0.f};
    #pragma unroll
    for (int jc = 0; jc < 10; ++jc) {
        const int jcol = (jcbase + jc) * 16 + lr;
        #pragma unroll
        for (int rr = 0; rr < 4; ++rr) {
            const int iloc = 16 * w + 4 * lhi + rr;
            const bool ok = (jcol >= iloc) && (jcol <= iloc + ATTN_) && (jcol >= lo0);
            const float p = ok ? __expf(fminf(sacc[jc][rr] * scale, 80.f)) : 0.f;
            lsum[rr] += p;
            myP[(4 * lhi + rr) * 200 + jcol] = f2bf(p);
        }
    }
    #pragma unroll
    for (int rr = 0; rr < 4; ++rr) {
        float s = lsum[rr];
        s += __shfl_xor(s, 1, 16);
        s += __shfl_xor(s, 2, 16);
        s += __shfl_xor(s, 4, 16);
        s += __shfl_xor(s, 8, 16);
        lsum[rr] = s;
    }

    const int kcbase = w >> 1;
    f32x4 oacc[4];
    #pragma unroll
    for (int fn = 0; fn < 4; ++fn) oacc[fn] = (f32x4){0.f, 0.f, 0.f, 0.f};
    const unsigned vbase = lds_addr(&Vsh[0]) + (unsigned)(l * 8);

    for (int kc5 = 0; kc5 < 5; ++kc5) {
        const int kc = kcbase + kc5;
        bf16x8 pa = *(const bf16x8*)&myP[lr * 200 + kc * 32 + lhi * 8];
        u32x2 vlo[4], vhi[4];
        #pragma unroll
        for (int fn = 0; fn < 4; ++fn) {
            const unsigned addr = vbase + (unsigned)((fn * 3072 + kc * 256) * 2);
            asm volatile("ds_read_b64_tr_b16 %0, %1" : "=v"(vlo[fn]) : "v"(addr));
            asm volatile("ds_read_b64_tr_b16 %0, %1 offset:3072"
                         : "=v"(vhi[fn]) : "v"(addr));
        }
        asm volatile("s_waitcnt lgkmcnt(0)" ::: "memory");
        __builtin_amdgcn_sched_barrier(0);
        __builtin_amdgcn_s_setprio(1);
        #pragma unroll
        for (int fn = 0; fn < 4; ++fn) {
            union { u32x2 h[2]; bf16x8 v; } u;
            u.h[0] = vlo[fn]; u.h[1] = vhi[fn];
            oacc[fn] = __builtin_amdgcn_mfma_f32_16x16x32_bf16(
                pa, u.v, oacc[fn], 0, 0, 0);
        }
        __builtin_amdgcn_s_setprio(0);
    }

    float inv[4];
    #pragma unroll
    for (int rr = 0; rr < 4; ++rr) inv[rr] = 1.f / lsum[rr];
    #pragma unroll
    for (int fn = 0; fn < 4; ++fn)
        #pragma unroll
        for (int rr = 0; rr < 4; ++rr) {
            const int row = i0 + 16 * w + 4 * lhi + rr;
            oh[(size_t)row * 512 + fn * 16 + lr] = f2bf(oacc[fn][rr] * inv[rr]);
        }
}

// ---------------------------------------------------------------------------
extern "C" void kernel_launch(void* const* d_in, const int* in_sizes, int n_in,
                              void* d_out, int out_size, void* d_ws, size_t ws_size,
                              hipStream_t stream)
{
    const float* query = (const float*)d_in[0];
    const float* key   = (const float*)d_in[1];
    const float* value = (const float*)d_in[2];
    const float* W_q   = (const float*)d_in[3];
    const float* b_q   = (const float*)d_in[4];
    const float* W_k   = (const float*)d_in[5];
    const float* b_k   = (const float*)d_in[6];
    const float* W_v   = (const float*)d_in[7];
    const float* b_v   = (const float*)d_in[8];
    const float* W_o   = (const float*)d_in[9];
    const float* b_o   = (const float*)d_in[10];
    float* out = (float*)d_out;

    const size_t NX = (size_t)M_ * 512;
    const size_t NW = 512 * 512;
    unsigned short* wqb = (unsigned short*)d_ws;
    unsigned short* wkb = wqb + NW;
    unsigned short* wvb = wkb + NW;
    unsigned short* wob = wvb + NW;
    unsigned short* qp  = wob + NW;
    unsigned short* kp  = qp + NX;
    unsigned short* vp  = kp + NX;
    unsigned short* ap  = vp + NX;

    const int NW8 = (int)(NW / 8);

    CvtA a;
    a.c[0] = { W_q, wqb, NW8 };
    a.c[1] = { W_k, wkb, NW8 };
    a.c[2] = { W_v, wvb, NW8 };
    a.c[3] = { W_o, wob, NW8 };
    cvt_multi<<<dim3(32, 4), 256, 0, stream>>>(a);

    GArgs qa;
    qa.A[0] = query; qa.A[1] = key; qa.A[2] = value;
    qa.Wt[0] = wqb;  qa.Wt[1] = wkb; qa.Wt[2] = wvb;
    qa.bias[0] = b_q; qa.bias[1] = b_k; qa.bias[2] = b_v;
    qa.C[0] = qp; qa.C[1] = kp; qa.C[2] = vp;
    gemm128<true><<<768, 256, 0, stream>>>(qa);   // 192 m-groups x 4 nt

    attn_mfma<<<dim3(32, 8, 4), 256, 0, stream>>>(qp, kp, vp, ap);

    GArgs oa;
    oa.A[0] = ap; oa.A[1] = ap; oa.A[2] = ap;
    oa.Wt[0] = wob; oa.Wt[1] = wob; oa.Wt[2] = wob;
    oa.bias[0] = b_o; oa.bias[1] = b_o; oa.bias[2] = b_o;
    oa.C[0] = out; oa.C[1] = out; oa.C[2] = out;
    gemm128<false><<<256, 256, 0, stream>>>(oa);  // 64 m-groups x 4 nt
}